// Round 1
// baseline (302.545 us; speedup 1.0000x reference)
//
#include <hip/hip_runtime.h>

// ShuffledGroupWhitening on MI355X.
// x: [3*8192, 1024] f32, perms: [3,1024] i32.
// Per (view s, group g): gather 16 permuted cols, center over batch,
// whiten with cov^{-1/2} (Newton-Schulz), scatter back (same col set).

constexpr int D_FEAT  = 1024;
constexpr int NGROUP  = 64;
constexpr int GD      = 16;     // group dim
constexpr int NB      = 8192;   // rows per view
constexpr int NVIEW   = 3;
constexpr int RPB     = 32;     // rows per block (pass 1 & 3)
constexpr int CHUNK1  = 8;      // rows staged in LDS per iter (pass 1)
constexpr int CHUNK3  = 4;      // rows staged in LDS per iter (pass 3)

// workspace layout (floats)
constexpr int SXX_OFF = 0;                                  // [3][64][16][16]
constexpr int SX_OFF  = NVIEW * NGROUP * GD * GD;           // 49152: [3][1024]
constexpr int W_OFF   = SX_OFF + NVIEW * D_FEAT;            // 52224: [3][64][16][16]
constexpr int STATS_FLOATS = W_OFF;                         // region zeroed per call

// ---------------- Pass 1: per-group Sxx and Sx ----------------
// block: 256 threads; thread = (g = tid>>2, q = tid&3).
// Thread accumulates acc[i][jj] = sum_rows v[i]*v[q*4+jj] (full 16x4 slab)
// and sacc[jj] = sum_rows v[q*4+jj]. Atomic-added to ws at the end.
__global__ __launch_bounds__(256) void k_stats(const float* __restrict__ x,
                                               const int* __restrict__ perms,
                                               float* __restrict__ ws) {
    __shared__ float lds[CHUNK1][D_FEAT];
    const int s   = blockIdx.y;
    const int rb  = blockIdx.x;
    const int tid = threadIdx.x;
    const int g   = tid >> 2;
    const int q   = tid & 3;

    int pcol[GD];
#pragma unroll
    for (int e = 0; e < GD; ++e) pcol[e] = perms[s * D_FEAT + g * GD + e];
    int pcolq[4];
#pragma unroll
    for (int jj = 0; jj < 4; ++jj) pcolq[jj] = perms[s * D_FEAT + g * GD + q * 4 + jj];

    float acc[GD][4];
#pragma unroll
    for (int i = 0; i < GD; ++i)
#pragma unroll
        for (int jj = 0; jj < 4; ++jj) acc[i][jj] = 0.0f;
    float sacc[4] = {0.0f, 0.0f, 0.0f, 0.0f};

    const float* xbase = x + (size_t)(s * NB + rb * RPB) * D_FEAT;

    for (int r0 = 0; r0 < RPB; r0 += CHUNK1) {
        // stage CHUNK1 rows, coalesced float4 (row t loaded by all 256 threads)
#pragma unroll
        for (int t = 0; t < CHUNK1; ++t) {
            *(float4*)&lds[t][tid * 4] =
                *(const float4*)&xbase[(size_t)(r0 + t) * D_FEAT + tid * 4];
        }
        __syncthreads();
#pragma unroll 2
        for (int r = 0; r < CHUNK1; ++r) {
            float v[GD];
#pragma unroll
            for (int e = 0; e < GD; ++e) v[e] = lds[r][pcol[e]];
            float vq[4];
#pragma unroll
            for (int jj = 0; jj < 4; ++jj) vq[jj] = lds[r][pcolq[jj]];
#pragma unroll
            for (int jj = 0; jj < 4; ++jj) sacc[jj] += vq[jj];
#pragma unroll
            for (int i = 0; i < GD; ++i)
#pragma unroll
                for (int jj = 0; jj < 4; ++jj) acc[i][jj] += v[i] * vq[jj];
        }
        __syncthreads();
    }

    float* sxx = ws + SXX_OFF + (size_t)((s * NGROUP + g) * GD) * GD;
#pragma unroll
    for (int i = 0; i < GD; ++i)
#pragma unroll
        for (int jj = 0; jj < 4; ++jj)
            atomicAdd(&sxx[i * GD + q * 4 + jj], acc[i][jj]);
    float* sx = ws + SX_OFF + s * D_FEAT + g * GD;
#pragma unroll
    for (int jj = 0; jj < 4; ++jj) atomicAdd(&sx[q * 4 + jj], sacc[jj]);
}

// ---------------- Pass 2: W = cov^{-1/2} via Newton-Schulz ----------------
// one block per (s,g); thread = (i = tid>>4, j = tid&15) entry of 16x16.
__global__ __launch_bounds__(256) void k_invsqrt(float* __restrict__ ws) {
    __shared__ float Ym[GD][GD];
    __shared__ float Zm[GD][GD];
    __shared__ float Tm[GD][GD];
    const int bx = blockIdx.x;
    const int s = bx / NGROUP, g = bx % NGROUP;
    const int tid = threadIdx.x;
    const int i = tid >> 4, j = tid & 15;
    const float invB = 1.0f / (float)NB;

    const float sxx = ws[SXX_OFF + (size_t)((s * NGROUP + g) * GD + i) * GD + j];
    const float mui = ws[SX_OFF + s * D_FEAT + g * GD + i] * invB;
    const float muj = ws[SX_OFF + s * D_FEAT + g * GD + j] * invB;
    const float a = sxx * invB - mui * muj;   // cov entry

    Ym[i][j] = a;
    __syncthreads();
    float tr = 0.0f;
#pragma unroll
    for (int k = 0; k < GD; ++k) tr += Ym[k][k];
    const float sc = tr * (1.0f / (float)GD);   // ~1.0 for N(0,1) data
    const float inv_sc = 1.0f / sc;
    __syncthreads();                            // all trace reads done
    Ym[i][j] = a * inv_sc;                      // normalized A, eig in ~[0.9,1.1]
    Zm[i][j] = (i == j) ? 1.0f : 0.0f;
    __syncthreads();

    float zn = (i == j) ? 1.0f : 0.0f;
    for (int it = 0; it < 6; ++it) {
        float t = 0.0f;
#pragma unroll
        for (int k = 0; k < GD; ++k) t += Zm[i][k] * Ym[k][j];
        t = ((i == j) ? 1.5f : 0.0f) - 0.5f * t;
        Tm[i][j] = t;                 // Tm not read since last barrier: safe
        __syncthreads();
        float yn = 0.0f;
        zn = 0.0f;
#pragma unroll
        for (int k = 0; k < GD; ++k) {
            yn += Ym[i][k] * Tm[k][j];
            zn += Tm[i][k] * Zm[k][j];
        }
        __syncthreads();              // all reads done before overwrite
        Ym[i][j] = yn;
        Zm[i][j] = zn;
        __syncthreads();
    }
    // W = Z * sc^{-1/2}
    ws[W_OFF + (size_t)((s * NGROUP + g) * GD + i) * GD + j] = zn * rsqrtf(sc);
}

// ---------------- Pass 3: y = (x_gathered - mu) @ W, scattered back ----------------
// block: 256 threads; thread = (g = tid>>2, q = tid&3) owns W[:, q*4..q*4+3] in regs.
__global__ __launch_bounds__(256) void k_apply(const float* __restrict__ x,
                                               const int* __restrict__ perms,
                                               const float* __restrict__ ws,
                                               float* __restrict__ out) {
    __shared__ float ldsin[CHUNK3][D_FEAT];
    __shared__ float ldsout[CHUNK3][D_FEAT];
    const int s   = blockIdx.y;
    const int rb  = blockIdx.x;
    const int tid = threadIdx.x;
    const int g   = tid >> 2;
    const int q   = tid & 3;
    const float invB = 1.0f / (float)NB;

    int pcol[GD];
#pragma unroll
    for (int e = 0; e < GD; ++e) pcol[e] = perms[s * D_FEAT + g * GD + e];
    int pcolq[4];
#pragma unroll
    for (int jj = 0; jj < 4; ++jj) pcolq[jj] = perms[s * D_FEAT + g * GD + q * 4 + jj];

    // W columns for this thread: w[e][ii] = W[s,g][e][q*4+ii]
    const float* Wp = ws + W_OFF + (size_t)(s * NGROUP + g) * GD * GD;
    float w[GD][4];
#pragma unroll
    for (int e = 0; e < GD; ++e) {
        float4 t4 = *(const float4*)&Wp[e * GD + q * 4];
        w[e][0] = t4.x; w[e][1] = t4.y; w[e][2] = t4.z; w[e][3] = t4.w;
    }
    // bias[ii] = sum_e mu[e] * w[e][ii]  (fold centering into the GEMV)
    float bias[4] = {0.0f, 0.0f, 0.0f, 0.0f};
#pragma unroll
    for (int e = 0; e < GD; ++e) {
        const float mu = ws[SX_OFF + s * D_FEAT + g * GD + e] * invB;
#pragma unroll
        for (int ii = 0; ii < 4; ++ii) bias[ii] += mu * w[e][ii];
    }

    const float* xbase = x + (size_t)(s * NB + rb * RPB) * D_FEAT;
    float* obase = out + (size_t)(s * NB + rb * RPB) * D_FEAT;

    for (int r0 = 0; r0 < RPB; r0 += CHUNK3) {
#pragma unroll
        for (int t = 0; t < CHUNK3; ++t) {
            *(float4*)&ldsin[t][tid * 4] =
                *(const float4*)&xbase[(size_t)(r0 + t) * D_FEAT + tid * 4];
        }
        __syncthreads();
#pragma unroll
        for (int r = 0; r < CHUNK3; ++r) {
            float v[GD];
#pragma unroll
            for (int e = 0; e < GD; ++e) v[e] = ldsin[r][pcol[e]];
            float u[4] = {-bias[0], -bias[1], -bias[2], -bias[3]};
#pragma unroll
            for (int e = 0; e < GD; ++e)
#pragma unroll
                for (int ii = 0; ii < 4; ++ii) u[ii] += v[e] * w[e][ii];
#pragma unroll
            for (int ii = 0; ii < 4; ++ii) ldsout[r][pcolq[ii]] = u[ii];
        }
        __syncthreads();
#pragma unroll
        for (int t = 0; t < CHUNK3; ++t) {
            *(float4*)&obase[(size_t)(r0 + t) * D_FEAT + tid * 4] =
                *(const float4*)&ldsout[t][tid * 4];
        }
        __syncthreads();
    }
}

extern "C" void kernel_launch(void* const* d_in, const int* in_sizes, int n_in,
                              void* d_out, int out_size, void* d_ws, size_t ws_size,
                              hipStream_t stream) {
    const float* x     = (const float*)d_in[0];
    const int*   perms = (const int*)d_in[1];
    float* out = (float*)d_out;
    float* ws  = (float*)d_ws;

    // zero the Sxx/Sx accumulators (ws is NOT re-poisoned between replays)
    hipMemsetAsync(ws, 0, (size_t)STATS_FLOATS * sizeof(float), stream);

    dim3 grid1(NB / RPB, NVIEW);       // (256, 3)
    k_stats<<<grid1, 256, 0, stream>>>(x, perms, ws);

    k_invsqrt<<<NVIEW * NGROUP, 256, 0, stream>>>(ws);

    dim3 grid3(NB / RPB, NVIEW);       // (256, 3)
    k_apply<<<grid3, 256, 0, stream>>>(x, perms, ws, out);
}

// Round 2
// 118.543 us; speedup vs baseline: 2.5522x; 2.5522x over previous
//
#include <hip/hip_runtime.h>

// ShuffledGroupWhitening on MI355X.
// x: [3*8192, 1024] f32, perms: [3,1024] i32.
// Per (view s, group g): gather 16 permuted cols, center over batch,
// whiten with cov^{-1/2} (Newton-Schulz), scatter back (same col set).
//
// R1 -> R2: k_stats' 13.4M contended atomicAdds (214 MB HBM write-through,
// 256-way same-address serialization) replaced by per-block partials +
// separate reduction kernel. No atomics anywhere on the hot path.

constexpr int D_FEAT  = 1024;
constexpr int NGROUP  = 64;
constexpr int GD      = 16;     // group dim
constexpr int NB      = 8192;   // rows per view
constexpr int NVIEW   = 3;
constexpr int CHUNK1  = 8;      // rows staged in LDS per iter (stats)
constexpr int CHUNK3  = 4;      // rows staged in LDS per iter (apply)

constexpr int SXX_FLOATS = NGROUP * GD * GD;                // 16384 per view
constexpr int PART_STRIDE = SXX_FLOATS + D_FEAT;            // 17408 per partial

// workspace layout (floats)
constexpr int SXX_OFF = 0;                                  // [3][64][16][16]
constexpr int SX_OFF  = NVIEW * SXX_FLOATS;                 // 49152: [3][1024]
constexpr int W_OFF   = SX_OFF + NVIEW * D_FEAT;            // 52224: [3][64][16][16]
constexpr int PART_OFF = W_OFF + NVIEW * SXX_FLOATS;        // 101376: partials
constexpr int STATS_FLOATS = W_OFF;                         // zeroed in atomic fallback

// ---------------- Pass 1a: per-block partial Sxx and Sx (no atomics) ----------------
// block: 256 threads; thread = (g = tid>>2, q = tid&3).
// Thread accumulates acc[i][jj] = sum_rows v[i]*v[q*4+jj] (full 16x4 slab)
// and sacc[jj] = sum_rows v[q*4+jj]; coalesced float4 store to its partial slice.
__global__ __launch_bounds__(256) void k_stats_part(const float* __restrict__ x,
                                                    const int* __restrict__ perms,
                                                    float* __restrict__ part,
                                                    int rpp, int P) {
    __shared__ float lds[CHUNK1][D_FEAT];
    const int s   = blockIdx.y;
    const int p   = blockIdx.x;
    const int tid = threadIdx.x;
    const int g   = tid >> 2;
    const int q   = tid & 3;

    int pcol[GD];
#pragma unroll
    for (int e = 0; e < GD; ++e) pcol[e] = perms[s * D_FEAT + g * GD + e];
    int pcolq[4];
#pragma unroll
    for (int jj = 0; jj < 4; ++jj) pcolq[jj] = perms[s * D_FEAT + g * GD + q * 4 + jj];

    float acc[GD][4];
#pragma unroll
    for (int i = 0; i < GD; ++i)
#pragma unroll
        for (int jj = 0; jj < 4; ++jj) acc[i][jj] = 0.0f;
    float sacc[4] = {0.0f, 0.0f, 0.0f, 0.0f};

    const float* xbase = x + (size_t)(s * NB + p * rpp) * D_FEAT;

    for (int r0 = 0; r0 < rpp; r0 += CHUNK1) {
        // stage CHUNK1 rows, coalesced float4 (row t loaded by all 256 threads)
#pragma unroll
        for (int t = 0; t < CHUNK1; ++t) {
            *(float4*)&lds[t][tid * 4] =
                *(const float4*)&xbase[(size_t)(r0 + t) * D_FEAT + tid * 4];
        }
        __syncthreads();
#pragma unroll 2
        for (int r = 0; r < CHUNK1; ++r) {
            float v[GD];
#pragma unroll
            for (int e = 0; e < GD; ++e) v[e] = lds[r][pcol[e]];
            float vq[4];
#pragma unroll
            for (int jj = 0; jj < 4; ++jj) vq[jj] = lds[r][pcolq[jj]];
#pragma unroll
            for (int jj = 0; jj < 4; ++jj) sacc[jj] += vq[jj];
#pragma unroll
            for (int i = 0; i < GD; ++i)
#pragma unroll
                for (int jj = 0; jj < 4; ++jj) acc[i][jj] += v[i] * vq[jj];
        }
        __syncthreads();
    }

    // partial layout: [s*P+p][ i*1024 + tid*4 + jj ] for Sxx, [16384 + tid*4 + jj] for Sx
    float* dst = part + (size_t)(s * P + p) * PART_STRIDE;
#pragma unroll
    for (int i = 0; i < GD; ++i) {
        float4 t4 = make_float4(acc[i][0], acc[i][1], acc[i][2], acc[i][3]);
        *(float4*)&dst[i * D_FEAT + tid * 4] = t4;
    }
    *(float4*)&dst[SXX_FLOATS + tid * 4] = make_float4(sacc[0], sacc[1], sacc[2], sacc[3]);
}

// ---------------- Pass 1b: reduce partials into ws Sxx/Sx ----------------
// one thread per stat entry (3*17408 = 52224 threads); coalesced reads per p-iter.
__global__ __launch_bounds__(256) void k_reduce(const float* __restrict__ part,
                                                float* __restrict__ ws, int P) {
    const int flat = blockIdx.x * 256 + threadIdx.x;
    if (flat >= NVIEW * PART_STRIDE) return;
    const int s = flat / PART_STRIDE;
    const int f = flat % PART_STRIDE;
    const float* src = part + (size_t)s * P * PART_STRIDE + f;
    float sum = 0.0f;
    for (int p = 0; p < P; ++p) sum += src[(size_t)p * PART_STRIDE];
    if (f < SXX_FLOATS) {
        // partial index: f = i*1024 + g*16 + (q*4+jj) = i*1024 + g*16 + j
        const int i = f >> 10;
        const int rest = f & 1023;
        const int g = rest >> 4;
        const int j = rest & 15;
        ws[SXX_OFF + (size_t)((s * NGROUP + g) * GD + i) * GD + j] = sum;
    } else {
        ws[SX_OFF + s * D_FEAT + (f - SXX_FLOATS)] = sum;
    }
}

// ---------------- Pass 1 (fallback): atomic version, only if ws is tiny ----------------
__global__ __launch_bounds__(256) void k_stats_atomic(const float* __restrict__ x,
                                                      const int* __restrict__ perms,
                                                      float* __restrict__ ws, int rpp) {
    __shared__ float lds[CHUNK1][D_FEAT];
    const int s   = blockIdx.y;
    const int p   = blockIdx.x;
    const int tid = threadIdx.x;
    const int g   = tid >> 2;
    const int q   = tid & 3;

    int pcol[GD];
#pragma unroll
    for (int e = 0; e < GD; ++e) pcol[e] = perms[s * D_FEAT + g * GD + e];
    int pcolq[4];
#pragma unroll
    for (int jj = 0; jj < 4; ++jj) pcolq[jj] = perms[s * D_FEAT + g * GD + q * 4 + jj];

    float acc[GD][4];
#pragma unroll
    for (int i = 0; i < GD; ++i)
#pragma unroll
        for (int jj = 0; jj < 4; ++jj) acc[i][jj] = 0.0f;
    float sacc[4] = {0.0f, 0.0f, 0.0f, 0.0f};

    const float* xbase = x + (size_t)(s * NB + p * rpp) * D_FEAT;
    for (int r0 = 0; r0 < rpp; r0 += CHUNK1) {
#pragma unroll
        for (int t = 0; t < CHUNK1; ++t) {
            *(float4*)&lds[t][tid * 4] =
                *(const float4*)&xbase[(size_t)(r0 + t) * D_FEAT + tid * 4];
        }
        __syncthreads();
#pragma unroll 2
        for (int r = 0; r < CHUNK1; ++r) {
            float v[GD];
#pragma unroll
            for (int e = 0; e < GD; ++e) v[e] = lds[r][pcol[e]];
#pragma unroll
            for (int jj = 0; jj < 4; ++jj) sacc[jj] += v[q * 4 + jj];
#pragma unroll
            for (int i = 0; i < GD; ++i)
#pragma unroll
                for (int jj = 0; jj < 4; ++jj) acc[i][jj] += v[i] * v[q * 4 + jj];
        }
        __syncthreads();
    }

    float* sxx = ws + SXX_OFF + (size_t)((s * NGROUP + g) * GD) * GD;
#pragma unroll
    for (int i = 0; i < GD; ++i)
#pragma unroll
        for (int jj = 0; jj < 4; ++jj)
            atomicAdd(&sxx[i * GD + q * 4 + jj], acc[i][jj]);
    float* sx = ws + SX_OFF + s * D_FEAT + g * GD;
#pragma unroll
    for (int jj = 0; jj < 4; ++jj) atomicAdd(&sx[q * 4 + jj], sacc[jj]);
}

// ---------------- Pass 2: W = cov^{-1/2} via Newton-Schulz ----------------
// one block per (s,g); thread = (i = tid>>4, j = tid&15) entry of 16x16.
__global__ __launch_bounds__(256) void k_invsqrt(float* __restrict__ ws) {
    __shared__ float Ym[GD][GD];
    __shared__ float Zm[GD][GD];
    __shared__ float Tm[GD][GD];
    const int bx = blockIdx.x;
    const int s = bx / NGROUP, g = bx % NGROUP;
    const int tid = threadIdx.x;
    const int i = tid >> 4, j = tid & 15;
    const float invB = 1.0f / (float)NB;

    const float sxx = ws[SXX_OFF + (size_t)((s * NGROUP + g) * GD + i) * GD + j];
    const float mui = ws[SX_OFF + s * D_FEAT + g * GD + i] * invB;
    const float muj = ws[SX_OFF + s * D_FEAT + g * GD + j] * invB;
    const float a = sxx * invB - mui * muj;   // cov entry

    Ym[i][j] = a;
    __syncthreads();
    float tr = 0.0f;
#pragma unroll
    for (int k = 0; k < GD; ++k) tr += Ym[k][k];
    const float sc = tr * (1.0f / (float)GD);   // ~1.0 for N(0,1) data
    const float inv_sc = 1.0f / sc;
    __syncthreads();                            // all trace reads done
    Ym[i][j] = a * inv_sc;                      // normalized A, eig in ~[0.9,1.1]
    Zm[i][j] = (i == j) ? 1.0f : 0.0f;
    __syncthreads();

    float zn = (i == j) ? 1.0f : 0.0f;
    for (int it = 0; it < 6; ++it) {
        float t = 0.0f;
#pragma unroll
        for (int k = 0; k < GD; ++k) t += Zm[i][k] * Ym[k][j];
        t = ((i == j) ? 1.5f : 0.0f) - 0.5f * t;
        Tm[i][j] = t;                 // Tm not read since last barrier: safe
        __syncthreads();
        float yn = 0.0f;
        zn = 0.0f;
#pragma unroll
        for (int k = 0; k < GD; ++k) {
            yn += Ym[i][k] * Tm[k][j];
            zn += Tm[i][k] * Zm[k][j];
        }
        __syncthreads();              // all reads done before overwrite
        Ym[i][j] = yn;
        Zm[i][j] = zn;
        __syncthreads();
    }
    // W = Z * sc^{-1/2}
    ws[W_OFF + (size_t)((s * NGROUP + g) * GD + i) * GD + j] = zn * rsqrtf(sc);
}

// ---------------- Pass 3: y = (x_gathered - mu) @ W, scattered back ----------------
// block: 256 threads; thread = (g = tid>>2, q = tid&3) owns W[:, q*4..q*4+3] in regs.
constexpr int RPB3 = 32;
__global__ __launch_bounds__(256) void k_apply(const float* __restrict__ x,
                                               const int* __restrict__ perms,
                                               const float* __restrict__ ws,
                                               float* __restrict__ out) {
    __shared__ float ldsin[CHUNK3][D_FEAT];
    __shared__ float ldsout[CHUNK3][D_FEAT];
    const int s   = blockIdx.y;
    const int rb  = blockIdx.x;
    const int tid = threadIdx.x;
    const int g   = tid >> 2;
    const int q   = tid & 3;
    const float invB = 1.0f / (float)NB;

    int pcol[GD];
#pragma unroll
    for (int e = 0; e < GD; ++e) pcol[e] = perms[s * D_FEAT + g * GD + e];
    int pcolq[4];
#pragma unroll
    for (int jj = 0; jj < 4; ++jj) pcolq[jj] = perms[s * D_FEAT + g * GD + q * 4 + jj];

    // W columns for this thread: w[e][ii] = W[s,g][e][q*4+ii]
    const float* Wp = ws + W_OFF + (size_t)(s * NGROUP + g) * GD * GD;
    float w[GD][4];
#pragma unroll
    for (int e = 0; e < GD; ++e) {
        float4 t4 = *(const float4*)&Wp[e * GD + q * 4];
        w[e][0] = t4.x; w[e][1] = t4.y; w[e][2] = t4.z; w[e][3] = t4.w;
    }
    // bias[ii] = sum_e mu[e] * w[e][ii]  (fold centering into the GEMV)
    float bias[4] = {0.0f, 0.0f, 0.0f, 0.0f};
#pragma unroll
    for (int e = 0; e < GD; ++e) {
        const float mu = ws[SX_OFF + s * D_FEAT + g * GD + e] * invB;
#pragma unroll
        for (int ii = 0; ii < 4; ++ii) bias[ii] += mu * w[e][ii];
    }

    const float* xbase = x + (size_t)(s * NB + rb * RPB3) * D_FEAT;
    float* obase = out + (size_t)(s * NB + rb * RPB3) * D_FEAT;

    for (int r0 = 0; r0 < RPB3; r0 += CHUNK3) {
#pragma unroll
        for (int t = 0; t < CHUNK3; ++t) {
            *(float4*)&ldsin[t][tid * 4] =
                *(const float4*)&xbase[(size_t)(r0 + t) * D_FEAT + tid * 4];
        }
        __syncthreads();
#pragma unroll
        for (int r = 0; r < CHUNK3; ++r) {
            float v[GD];
#pragma unroll
            for (int e = 0; e < GD; ++e) v[e] = ldsin[r][pcol[e]];
            float u[4] = {-bias[0], -bias[1], -bias[2], -bias[3]};
#pragma unroll
            for (int e = 0; e < GD; ++e)
#pragma unroll
                for (int ii = 0; ii < 4; ++ii) u[ii] += v[e] * w[e][ii];
#pragma unroll
            for (int ii = 0; ii < 4; ++ii) ldsout[r][pcolq[ii]] = u[ii];
        }
        __syncthreads();
#pragma unroll
        for (int t = 0; t < CHUNK3; ++t) {
            *(float4*)&obase[(size_t)(r0 + t) * D_FEAT + tid * 4] =
                *(const float4*)&ldsout[t][tid * 4];
        }
        __syncthreads();
    }
}

extern "C" void kernel_launch(void* const* d_in, const int* in_sizes, int n_in,
                              void* d_out, int out_size, void* d_ws, size_t ws_size,
                              hipStream_t stream) {
    const float* x     = (const float*)d_in[0];
    const int*   perms = (const int*)d_in[1];
    float* out = (float*)d_out;
    float* ws  = (float*)d_ws;

    // pick partial count P (per view) to fit ws; 128 -> 26.7 MB of partials
    int P = 128;
    while (P > 8 && (size_t)(PART_OFF + (size_t)NVIEW * P * PART_STRIDE) * 4 > ws_size)
        P >>= 1;

    if ((size_t)(PART_OFF + (size_t)NVIEW * P * PART_STRIDE) * 4 <= ws_size) {
        const int rpp = NB / P;
        dim3 grid1(P, NVIEW);
        k_stats_part<<<grid1, 256, 0, stream>>>(x, perms, ws + PART_OFF, rpp, P);
        const int nred = (NVIEW * PART_STRIDE + 255) / 256;   // 204
        k_reduce<<<nred, 256, 0, stream>>>(ws + PART_OFF, ws, P);
    } else {
        hipMemsetAsync(ws, 0, (size_t)STATS_FLOATS * sizeof(float), stream);
        dim3 grid1(256, NVIEW);
        k_stats_atomic<<<grid1, 256, 0, stream>>>(x, perms, ws, NB / 256);
    }

    k_invsqrt<<<NVIEW * NGROUP, 256, 0, stream>>>(ws);

    dim3 grid3(NB / RPB3, NVIEW);      // (256, 3)
    k_apply<<<grid3, 256, 0, stream>>>(x, perms, ws, out);
}

// Round 4
// 110.855 us; speedup vs baseline: 2.7292x; 1.0694x over previous
//
#include <hip/hip_runtime.h>
#include <stdint.h>

// ShuffledGroupWhitening on MI355X.
// x: [3*8192, 1024] f32, perms: [3,1024] i32.
// Per (view s, group g): gather 16 permuted cols, center over batch,
// whiten with cov^{-1/2} (Newton-Schulz), scatter back (same col set).
//
// R3 -> R4: R3's NaN traced to the global_load_lds staging path (only
// unproven mechanism). Reverted to register-staged double-buffering with
// plain float4 loads + ds_write (T14 pattern: issue loads after the barrier,
// consume at next iteration's ds_write -> latency hides under compute, and
// no barrier drains the in-flight loads). Kept: P1=256 w/ partials in d_out,
// cndmask vq selects, 8-way split reduce.

constexpr int D_FEAT  = 1024;
constexpr int NGROUP  = 64;
constexpr int GD      = 16;     // group dim
constexpr int NB      = 8192;   // rows per view
constexpr int NVIEW   = 3;

constexpr int P1      = 256;    // stats blocks per view (768 total = 3/CU)
constexpr int RPP1    = NB / P1;        // 32 rows per stats block
constexpr int C1      = 4;      // chunk rows (stats)
constexpr int RPB3    = 32;     // rows per apply block
constexpr int C3      = 4;      // chunk rows (apply)
constexpr int PSPLIT  = 8;      // reduce split factor

constexpr int SXX_FLOATS  = NGROUP * GD * GD;        // 16384 per view
constexpr int PART_STRIDE = SXX_FLOATS + D_FEAT;     // 17408 per partial
constexpr int ENT         = NVIEW * PART_STRIDE;     // 52224 stat entries

// ws layout (floats) — partials live in d_out, NOT here
constexpr int SXX_OFF = 0;                           // [3][64][16][16]
constexpr int SX_OFF  = NVIEW * SXX_FLOATS;          // 49152: [3][1024]
constexpr int W_OFF   = SX_OFF + NVIEW * D_FEAT;     // 52224: [3][64][16][16]
constexpr int RED_OFF = W_OFF + NVIEW * SXX_FLOATS;  // 101376: [8][52224]
// total ws use = RED_OFF + PSPLIT*ENT = 519168 floats ~ 2.1 MB

// ---------------- Pass 1a: per-block partial Sxx and Sx (no atomics) ----------------
// block: 256 threads; thread = (g = tid>>2, q = tid&3) accumulates the 16x4 slab
// acc[i][jj] = sum_rows v[i]*v[q*4+jj] and sacc[jj] = sum_rows v[q*4+jj].
__global__ __launch_bounds__(256, 3) void k_stats_part(const float* __restrict__ x,
                                                       const int* __restrict__ perms,
                                                       float* __restrict__ part) {
    __shared__ float buf[2][C1][D_FEAT];             // 32 KB double buffer
    const int s   = blockIdx.y;
    const int p   = blockIdx.x;
    const int tid = threadIdx.x;
    const int g   = tid >> 2;
    const int q   = tid & 3;

    int pcol[GD];
#pragma unroll
    for (int e = 0; e < GD; ++e) pcol[e] = perms[s * D_FEAT + g * GD + e];

    float acc[GD][4];
#pragma unroll
    for (int i = 0; i < GD; ++i)
#pragma unroll
        for (int jj = 0; jj < 4; ++jj) acc[i][jj] = 0.0f;
    float sacc[4] = {0.0f, 0.0f, 0.0f, 0.0f};

    const float* xbase = x + (size_t)(s * NB + p * RPP1) * D_FEAT;
    constexpr int NCH = RPP1 / C1;                   // 8 chunks

    // prologue: chunk 0 -> registers
    float4 rr[C1];
#pragma unroll
    for (int t = 0; t < C1; ++t)
        rr[t] = *(const float4*)&xbase[(size_t)t * D_FEAT + tid * 4];

    for (int k = 0; k < NCH; ++k) {
        // write chunk k regs -> LDS (vmcnt wait for rr happens here, one
        // compute-phase after the loads were issued)
#pragma unroll
        for (int t = 0; t < C1; ++t)
            *(float4*)&buf[k & 1][t][tid * 4] = rr[t];
        __syncthreads();                             // chunk k visible to all
        if (k + 1 < NCH) {                           // issue chunk k+1: flies under compute
            const float* nx = xbase + (size_t)(k + 1) * C1 * D_FEAT;
#pragma unroll
            for (int t = 0; t < C1; ++t)
                rr[t] = *(const float4*)&nx[(size_t)t * D_FEAT + tid * 4];
        }
        const float (*cb)[D_FEAT] = buf[k & 1];
#pragma unroll
        for (int r = 0; r < C1; ++r) {
            float v[GD];
#pragma unroll
            for (int e = 0; e < GD; ++e) v[e] = cb[r][pcol[e]];
            // vq[jj] = v[q*4+jj] via cndmask (static indices; no LDS re-read)
            float vq[4];
#pragma unroll
            for (int jj = 0; jj < 4; ++jj)
                vq[jj] = (q & 2) ? ((q & 1) ? v[12 + jj] : v[8 + jj])
                                 : ((q & 1) ? v[4 + jj]  : v[jj]);
#pragma unroll
            for (int jj = 0; jj < 4; ++jj) sacc[jj] += vq[jj];
#pragma unroll
            for (int i = 0; i < GD; ++i)
#pragma unroll
                for (int jj = 0; jj < 4; ++jj)
                    acc[i][jj] = fmaf(v[i], vq[jj], acc[i][jj]);
        }
        __syncthreads();   // everyone done reading buf[k&1] before iter k+2 rewrites it?
                           // (not needed for k&1 parity safety, but cheap and guards
                           //  the k+1 ds_write vs slow-wave compute(k) on SAME parity
                           //  never occurs; kept minimal: see note below)
    }
    // NOTE: the trailing barrier above also makes the loop robust regardless of
    // wave skew (write(k+2,parity k) strictly after all reads(k,parity k)).

    // partial layout: [s*P1+p][ i*1024 + tid*4 + jj ] for Sxx, [16384 + tid*4 + jj] for Sx
    float* dst = part + (size_t)(s * P1 + p) * PART_STRIDE;
#pragma unroll
    for (int i = 0; i < GD; ++i)
        *(float4*)&dst[i * D_FEAT + tid * 4] =
            make_float4(acc[i][0], acc[i][1], acc[i][2], acc[i][3]);
    *(float4*)&dst[SXX_FLOATS + tid * 4] = make_float4(sacc[0], sacc[1], sacc[2], sacc[3]);
}

// ---------------- Pass 1b: reduce partials, stage 1 (P1 -> PSPLIT) ----------------
__global__ __launch_bounds__(256) void k_reduce1(const float* __restrict__ part,
                                                 float* __restrict__ red) {
    const int f = blockIdx.x * 256 + threadIdx.x;
    if (f >= ENT) return;
    const int s = f / PART_STRIDE, ff = f % PART_STRIDE;
    constexpr int PER = P1 / PSPLIT;                 // 32
    const float* src = part + ((size_t)s * P1 + blockIdx.y * PER) * PART_STRIDE + ff;
    float sum = 0.0f;
#pragma unroll 8
    for (int p = 0; p < PER; ++p) sum += src[(size_t)p * PART_STRIDE];
    red[(size_t)blockIdx.y * ENT + f] = sum;
}

// ---------------- Pass 1c: reduce stage 2 (PSPLIT -> 1) + scatter into ws ----------------
__global__ __launch_bounds__(256) void k_reduce2(const float* __restrict__ red,
                                                 float* __restrict__ ws) {
    const int f = blockIdx.x * 256 + threadIdx.x;
    if (f >= ENT) return;
    float sum = 0.0f;
#pragma unroll
    for (int pp = 0; pp < PSPLIT; ++pp) sum += red[(size_t)pp * ENT + f];
    const int s = f / PART_STRIDE, rest = f % PART_STRIDE;
    if (rest < SXX_FLOATS) {
        // rest = i*1024 + g*16 + j
        const int i = rest >> 10;
        const int g = (rest & 1023) >> 4;
        const int j = rest & 15;
        ws[SXX_OFF + (size_t)((s * NGROUP + g) * GD + i) * GD + j] = sum;
    } else {
        ws[SX_OFF + s * D_FEAT + (rest - SXX_FLOATS)] = sum;
    }
}

// ---------------- Pass 2: W = cov^{-1/2} via Newton-Schulz ----------------
// one block per (s,g); thread = (i = tid>>4, j = tid&15) entry of 16x16.
__global__ __launch_bounds__(256) void k_invsqrt(float* __restrict__ ws) {
    __shared__ float Ym[GD][GD];
    __shared__ float Zm[GD][GD];
    __shared__ float Tm[GD][GD];
    const int bx = blockIdx.x;
    const int s = bx / NGROUP, g = bx % NGROUP;
    const int tid = threadIdx.x;
    const int i = tid >> 4, j = tid & 15;
    const float invB = 1.0f / (float)NB;

    const float sxx = ws[SXX_OFF + (size_t)((s * NGROUP + g) * GD + i) * GD + j];
    const float mui = ws[SX_OFF + s * D_FEAT + g * GD + i] * invB;
    const float muj = ws[SX_OFF + s * D_FEAT + g * GD + j] * invB;
    const float a = sxx * invB - mui * muj;   // cov entry

    Ym[i][j] = a;
    __syncthreads();
    float tr = 0.0f;
#pragma unroll
    for (int k = 0; k < GD; ++k) tr += Ym[k][k];
    const float sc = tr * (1.0f / (float)GD);   // ~1.0 for N(0,1) data
    const float inv_sc = 1.0f / sc;
    __syncthreads();                            // all trace reads done
    Ym[i][j] = a * inv_sc;                      // normalized A, eig in ~[0.9,1.1]
    Zm[i][j] = (i == j) ? 1.0f : 0.0f;
    __syncthreads();

    float zn = (i == j) ? 1.0f : 0.0f;
    for (int it = 0; it < 6; ++it) {
        float t = 0.0f;
#pragma unroll
        for (int k = 0; k < GD; ++k) t += Zm[i][k] * Ym[k][j];
        t = ((i == j) ? 1.5f : 0.0f) - 0.5f * t;
        Tm[i][j] = t;
        __syncthreads();
        float yn = 0.0f;
        zn = 0.0f;
#pragma unroll
        for (int k = 0; k < GD; ++k) {
            yn += Ym[i][k] * Tm[k][j];
            zn += Tm[i][k] * Zm[k][j];
        }
        __syncthreads();
        Ym[i][j] = yn;
        Zm[i][j] = zn;
        __syncthreads();
    }
    // W = Z * sc^{-1/2}
    ws[W_OFF + (size_t)((s * NGROUP + g) * GD + i) * GD + j] = zn * rsqrtf(sc);
}

// ---------------- Pass 3: y = (x_gathered - mu) @ W, scattered back ----------------
// block: 256 threads; thread = (g = tid>>2, q = tid&3) owns W[:, q*4..q*4+3] in regs.
__global__ __launch_bounds__(256, 3) void k_apply(const float* __restrict__ x,
                                                  const int* __restrict__ perms,
                                                  const float* __restrict__ ws,
                                                  float* __restrict__ out) {
    __shared__ float bin[2][C3][D_FEAT];             // 32 KB double-buffered input
    __shared__ float bout[C3][D_FEAT];               // 16 KB output staging
    const int s   = blockIdx.y;
    const int rb  = blockIdx.x;
    const int tid = threadIdx.x;
    const int g   = tid >> 2;
    const int q   = tid & 3;
    const float invB = 1.0f / (float)NB;

    int pcol[GD];
#pragma unroll
    for (int e = 0; e < GD; ++e) pcol[e] = perms[s * D_FEAT + g * GD + e];
    int pcolq[4];
#pragma unroll
    for (int jj = 0; jj < 4; ++jj)
        pcolq[jj] = (q & 2) ? ((q & 1) ? pcol[12 + jj] : pcol[8 + jj])
                            : ((q & 1) ? pcol[4 + jj]  : pcol[jj]);

    // W columns for this thread: w[e][ii] = W[s,g][e][q*4+ii]
    const float* Wp = ws + W_OFF + (size_t)(s * NGROUP + g) * GD * GD;
    float w[GD][4];
#pragma unroll
    for (int e = 0; e < GD; ++e) {
        float4 t4 = *(const float4*)&Wp[e * GD + q * 4];
        w[e][0] = t4.x; w[e][1] = t4.y; w[e][2] = t4.z; w[e][3] = t4.w;
    }
    // bias[ii] = sum_e mu[e] * w[e][ii]  (fold centering into the GEMV)
    float bias[4] = {0.0f, 0.0f, 0.0f, 0.0f};
#pragma unroll
    for (int e = 0; e < GD; ++e) {
        const float mu = ws[SX_OFF + s * D_FEAT + g * GD + e] * invB;
#pragma unroll
        for (int ii = 0; ii < 4; ++ii) bias[ii] += mu * w[e][ii];
    }

    const float* xbase = x + (size_t)(s * NB + rb * RPB3) * D_FEAT;
    float* obase = out + (size_t)(s * NB + rb * RPB3) * D_FEAT;
    constexpr int NCH = RPB3 / C3;                   // 8 chunks

    float4 rr[C3];
#pragma unroll
    for (int t = 0; t < C3; ++t)
        rr[t] = *(const float4*)&xbase[(size_t)t * D_FEAT + tid * 4];

    for (int k = 0; k < NCH; ++k) {
#pragma unroll
        for (int t = 0; t < C3; ++t)
            *(float4*)&bin[k & 1][t][tid * 4] = rr[t];
        __syncthreads();                             // bin[k&1] visible; bout(k-1) reads done
        if (k + 1 < NCH) {                           // issue chunk k+1 loads under compute
            const float* nx = xbase + (size_t)(k + 1) * C3 * D_FEAT;
#pragma unroll
            for (int t = 0; t < C3; ++t)
                rr[t] = *(const float4*)&nx[(size_t)t * D_FEAT + tid * 4];
        }
        const float (*cb)[D_FEAT] = bin[k & 1];
#pragma unroll
        for (int r = 0; r < C3; ++r) {
            float v[GD];
#pragma unroll
            for (int e = 0; e < GD; ++e) v[e] = cb[r][pcol[e]];
            float u[4] = {-bias[0], -bias[1], -bias[2], -bias[3]};
#pragma unroll
            for (int e = 0; e < GD; ++e)
#pragma unroll
                for (int ii = 0; ii < 4; ++ii) u[ii] = fmaf(v[e], w[e][ii], u[ii]);
#pragma unroll
            for (int ii = 0; ii < 4; ++ii) bout[r][pcolq[ii]] = u[ii];
        }
        __syncthreads();                             // bout complete
        float* ob = obase + (size_t)k * C3 * D_FEAT;
#pragma unroll
        for (int t = 0; t < C3; ++t)
            *(float4*)&ob[(size_t)t * D_FEAT + tid * 4] =
                *(const float4*)&bout[t][tid * 4];
    }
}

extern "C" void kernel_launch(void* const* d_in, const int* in_sizes, int n_in,
                              void* d_out, int out_size, void* d_ws, size_t ws_size,
                              hipStream_t stream) {
    const float* x     = (const float*)d_in[0];
    const int*   perms = (const int*)d_in[1];
    float* out = (float*)d_out;
    float* ws  = (float*)d_ws;

    // Partials (3*256*17408 floats = 53.5 MB) live in d_out: it is 100 MB and
    // k_apply fully overwrites every element afterwards. ws only needs 2.1 MB.
    float* part = out;

    dim3 g1(P1, NVIEW);                              // 768 blocks = 3/CU
    k_stats_part<<<g1, 256, 0, stream>>>(x, perms, part);

    dim3 gr1((ENT + 255) / 256, PSPLIT);             // (204, 8)
    k_reduce1<<<gr1, 256, 0, stream>>>(part, ws + RED_OFF);
    k_reduce2<<<(ENT + 255) / 256, 256, 0, stream>>>(ws + RED_OFF, ws);

    k_invsqrt<<<NVIEW * NGROUP, 256, 0, stream>>>(ws);

    dim3 g3(NB / RPB3, NVIEW);                       // 768 blocks = 3/CU
    k_apply<<<g3, 256, 0, stream>>>(x, perms, ws, out);
}

// Round 5
// 109.981 us; speedup vs baseline: 2.7509x; 1.0079x over previous
//
#include <hip/hip_runtime.h>
#include <stdint.h>

// ShuffledGroupWhitening on MI355X.
// x: [3*8192, 1024] f32, perms: [3,1024] i32.
// Per (view s, group g): gather 16 permuted cols, center over batch,
// whiten with cov^{-1/2} (Newton-Schulz), scatter back (same col set).
//
// R4 -> R5: stats' LDS pipe carried 4x redundant gathers (each quad-lane
// re-read all 16 group values). Now each lane gathers only its own 4 values
// (coalesced perm indices) and v[16] is rebuilt with quad_perm DPP broadcasts
// (VALU pipe, bit-identical). Stats loop also cut to ONE barrier per chunk
// (double-buffer parity makes the second redundant). Same DPP trick in apply.

constexpr int D_FEAT  = 1024;
constexpr int NGROUP  = 64;
constexpr int GD      = 16;     // group dim
constexpr int NB      = 8192;   // rows per view
constexpr int NVIEW   = 3;

constexpr int P1      = 256;    // stats blocks per view (768 total = 3/CU)
constexpr int RPP1    = NB / P1;        // 32 rows per stats block
constexpr int C1      = 4;      // chunk rows (stats)
constexpr int RPB3    = 32;     // rows per apply block
constexpr int C3      = 4;      // chunk rows (apply)
constexpr int PSPLIT  = 8;      // reduce split factor

constexpr int SXX_FLOATS  = NGROUP * GD * GD;        // 16384 per view
constexpr int PART_STRIDE = SXX_FLOATS + D_FEAT;     // 17408 per partial
constexpr int ENT         = NVIEW * PART_STRIDE;     // 52224 stat entries

// ws layout (floats) — partials live in d_out, NOT here
constexpr int SXX_OFF = 0;                           // [3][64][16][16]
constexpr int SX_OFF  = NVIEW * SXX_FLOATS;          // 49152: [3][1024]
constexpr int W_OFF   = SX_OFF + NVIEW * D_FEAT;     // 52224: [3][64][16][16]
constexpr int RED_OFF = W_OFF + NVIEW * SXX_FLOATS;  // 101376: [8][52224]
// total ws use = RED_OFF + PSPLIT*ENT = 519168 floats ~ 2.1 MB

// quad broadcast: every lane gets lane ((lane&~3)+B)'s value. Pure VALU DPP.
template <int B>
__device__ __forceinline__ float qbc(float x) {
    return __int_as_float(__builtin_amdgcn_mov_dpp(
        __float_as_int(x), B * 0x55 /*quad_perm[B,B,B,B]*/, 0xF, 0xF, true));
}

// ---------------- Pass 1a: per-block partial Sxx and Sx (no atomics) ----------------
// block: 256 threads; thread = (g = tid>>2, q = tid&3): gathers its own quad
// vq[4] from LDS, rebuilds v[16] via DPP, accumulates acc[i][jj] = sum v[i]*vq[jj].
__global__ __launch_bounds__(256, 3) void k_stats_part(const float* __restrict__ x,
                                                       const int* __restrict__ perms,
                                                       float* __restrict__ part) {
    __shared__ float buf[2][C1][D_FEAT];             // 32 KB double buffer
    const int s   = blockIdx.y;
    const int p   = blockIdx.x;
    const int tid = threadIdx.x;

    // this thread's 4 permuted column indices (coalesced int4-ish load)
    int pcolq[4];
#pragma unroll
    for (int jj = 0; jj < 4; ++jj) pcolq[jj] = perms[s * D_FEAT + tid * 4 + jj];

    float acc[GD][4];
#pragma unroll
    for (int i = 0; i < GD; ++i)
#pragma unroll
        for (int jj = 0; jj < 4; ++jj) acc[i][jj] = 0.0f;
    float sacc[4] = {0.0f, 0.0f, 0.0f, 0.0f};

    const float* xbase = x + (size_t)(s * NB + p * RPP1) * D_FEAT;
    constexpr int NCH = RPP1 / C1;                   // 8 chunks

    // prologue: chunk 0 -> registers
    float4 rr[C1];
#pragma unroll
    for (int t = 0; t < C1; ++t)
        rr[t] = *(const float4*)&xbase[(size_t)t * D_FEAT + tid * 4];

    for (int k = 0; k < NCH; ++k) {
        // regs -> LDS (vmcnt wait for rr lands here, one phase after issue)
#pragma unroll
        for (int t = 0; t < C1; ++t)
            *(float4*)&buf[k & 1][t][tid * 4] = rr[t];
        __syncthreads();   // single barrier/chunk: write(k+2,par p) is fenced
                           // from reads(k,par p) by barrier(k+1). Safe.
        if (k + 1 < NCH) {                           // prefetch flies under compute
            const float* nx = xbase + (size_t)(k + 1) * C1 * D_FEAT;
#pragma unroll
            for (int t = 0; t < C1; ++t)
                rr[t] = *(const float4*)&nx[(size_t)t * D_FEAT + tid * 4];
        }
        const float (*cb)[D_FEAT] = buf[k & 1];
#pragma unroll
        for (int r = 0; r < C1; ++r) {
            float vq[4];
#pragma unroll
            for (int jj = 0; jj < 4; ++jj) vq[jj] = cb[r][pcolq[jj]];
            // rebuild the group's 16 values from the quad via DPP broadcasts
            float v[GD];
#pragma unroll
            for (int jj = 0; jj < 4; ++jj) {
                v[0  + jj] = qbc<0>(vq[jj]);
                v[4  + jj] = qbc<1>(vq[jj]);
                v[8  + jj] = qbc<2>(vq[jj]);
                v[12 + jj] = qbc<3>(vq[jj]);
            }
#pragma unroll
            for (int jj = 0; jj < 4; ++jj) sacc[jj] += vq[jj];
#pragma unroll
            for (int i = 0; i < GD; ++i)
#pragma unroll
                for (int jj = 0; jj < 4; ++jj)
                    acc[i][jj] = fmaf(v[i], vq[jj], acc[i][jj]);
        }
    }

    // partial layout: [s*P1+p][ i*1024 + tid*4 + jj ] for Sxx, [16384 + tid*4 + jj] for Sx
    float* dst = part + (size_t)(s * P1 + p) * PART_STRIDE;
#pragma unroll
    for (int i = 0; i < GD; ++i)
        *(float4*)&dst[i * D_FEAT + tid * 4] =
            make_float4(acc[i][0], acc[i][1], acc[i][2], acc[i][3]);
    *(float4*)&dst[SXX_FLOATS + tid * 4] = make_float4(sacc[0], sacc[1], sacc[2], sacc[3]);
}

// ---------------- Pass 1b: reduce partials, stage 1 (P1 -> PSPLIT) ----------------
__global__ __launch_bounds__(256) void k_reduce1(const float* __restrict__ part,
                                                 float* __restrict__ red) {
    const int f = blockIdx.x * 256 + threadIdx.x;
    if (f >= ENT) return;
    const int s = f / PART_STRIDE, ff = f % PART_STRIDE;
    constexpr int PER = P1 / PSPLIT;                 // 32
    const float* src = part + ((size_t)s * P1 + blockIdx.y * PER) * PART_STRIDE + ff;
    float sum = 0.0f;
#pragma unroll 8
    for (int p = 0; p < PER; ++p) sum += src[(size_t)p * PART_STRIDE];
    red[(size_t)blockIdx.y * ENT + f] = sum;
}

// ---------------- Pass 1c: reduce stage 2 (PSPLIT -> 1) + scatter into ws ----------------
__global__ __launch_bounds__(256) void k_reduce2(const float* __restrict__ red,
                                                 float* __restrict__ ws) {
    const int f = blockIdx.x * 256 + threadIdx.x;
    if (f >= ENT) return;
    float sum = 0.0f;
#pragma unroll
    for (int pp = 0; pp < PSPLIT; ++pp) sum += red[(size_t)pp * ENT + f];
    const int s = f / PART_STRIDE, rest = f % PART_STRIDE;
    if (rest < SXX_FLOATS) {
        // rest = i*1024 + g*16 + j
        const int i = rest >> 10;
        const int g = (rest & 1023) >> 4;
        const int j = rest & 15;
        ws[SXX_OFF + (size_t)((s * NGROUP + g) * GD + i) * GD + j] = sum;
    } else {
        ws[SX_OFF + s * D_FEAT + (rest - SXX_FLOATS)] = sum;
    }
}

// ---------------- Pass 2: W = cov^{-1/2} via Newton-Schulz ----------------
// one block per (s,g); thread = (i = tid>>4, j = tid&15) entry of 16x16.
__global__ __launch_bounds__(256) void k_invsqrt(float* __restrict__ ws) {
    __shared__ float Ym[GD][GD];
    __shared__ float Zm[GD][GD];
    __shared__ float Tm[GD][GD];
    const int bx = blockIdx.x;
    const int s = bx / NGROUP, g = bx % NGROUP;
    const int tid = threadIdx.x;
    const int i = tid >> 4, j = tid & 15;
    const float invB = 1.0f / (float)NB;

    const float sxx = ws[SXX_OFF + (size_t)((s * NGROUP + g) * GD + i) * GD + j];
    const float mui = ws[SX_OFF + s * D_FEAT + g * GD + i] * invB;
    const float muj = ws[SX_OFF + s * D_FEAT + g * GD + j] * invB;
    const float a = sxx * invB - mui * muj;   // cov entry

    Ym[i][j] = a;
    __syncthreads();
    float tr = 0.0f;
#pragma unroll
    for (int k = 0; k < GD; ++k) tr += Ym[k][k];
    const float sc = tr * (1.0f / (float)GD);   // ~1.0 for N(0,1) data
    const float inv_sc = 1.0f / sc;
    __syncthreads();                            // all trace reads done
    Ym[i][j] = a * inv_sc;                      // normalized A, eig in ~[0.9,1.1]
    Zm[i][j] = (i == j) ? 1.0f : 0.0f;
    __syncthreads();

    float zn = (i == j) ? 1.0f : 0.0f;
    for (int it = 0; it < 6; ++it) {
        float t = 0.0f;
#pragma unroll
        for (int k = 0; k < GD; ++k) t += Zm[i][k] * Ym[k][j];
        t = ((i == j) ? 1.5f : 0.0f) - 0.5f * t;
        Tm[i][j] = t;
        __syncthreads();
        float yn = 0.0f;
        zn = 0.0f;
#pragma unroll
        for (int k = 0; k < GD; ++k) {
            yn += Ym[i][k] * Tm[k][j];
            zn += Tm[i][k] * Zm[k][j];
        }
        __syncthreads();
        Ym[i][j] = yn;
        Zm[i][j] = zn;
        __syncthreads();
    }
    // W = Z * sc^{-1/2}
    ws[W_OFF + (size_t)((s * NGROUP + g) * GD + i) * GD + j] = zn * rsqrtf(sc);
}

// ---------------- Pass 3: y = (x_gathered - mu) @ W, scattered back ----------------
// block: 256 threads; thread = (g = tid>>2, q = tid&3) owns W[:, q*4..q*4+3] in regs;
// gathers its quad from LDS, rebuilds v[16] via DPP, scatters u[4] to bout.
__global__ __launch_bounds__(256, 3) void k_apply(const float* __restrict__ x,
                                                  const int* __restrict__ perms,
                                                  const float* __restrict__ ws,
                                                  float* __restrict__ out) {
    __shared__ float bin[2][C3][D_FEAT];             // 32 KB double-buffered input
    __shared__ float bout[C3][D_FEAT];               // 16 KB output staging
    const int s   = blockIdx.y;
    const int rb  = blockIdx.x;
    const int tid = threadIdx.x;
    const int g   = tid >> 2;
    const int q   = tid & 3;
    const float invB = 1.0f / (float)NB;

    int pcolq[4];
#pragma unroll
    for (int jj = 0; jj < 4; ++jj) pcolq[jj] = perms[s * D_FEAT + tid * 4 + jj];

    // W columns for this thread: w[e][ii] = W[s,g][e][q*4+ii]
    const float* Wp = ws + W_OFF + (size_t)(s * NGROUP + g) * GD * GD;
    float w[GD][4];
#pragma unroll
    for (int e = 0; e < GD; ++e) {
        float4 t4 = *(const float4*)&Wp[e * GD + q * 4];
        w[e][0] = t4.x; w[e][1] = t4.y; w[e][2] = t4.z; w[e][3] = t4.w;
    }
    // bias[ii] = sum_e mu[e] * w[e][ii]  (fold centering into the GEMV)
    float bias[4] = {0.0f, 0.0f, 0.0f, 0.0f};
#pragma unroll
    for (int e = 0; e < GD; ++e) {
        const float mu = ws[SX_OFF + s * D_FEAT + g * GD + e] * invB;
#pragma unroll
        for (int ii = 0; ii < 4; ++ii) bias[ii] += mu * w[e][ii];
    }

    const float* xbase = x + (size_t)(s * NB + rb * RPB3) * D_FEAT;
    float* obase = out + (size_t)(s * NB + rb * RPB3) * D_FEAT;
    constexpr int NCH = RPB3 / C3;                   // 8 chunks

    float4 rr[C3];
#pragma unroll
    for (int t = 0; t < C3; ++t)
        rr[t] = *(const float4*)&xbase[(size_t)t * D_FEAT + tid * 4];

    for (int k = 0; k < NCH; ++k) {
#pragma unroll
        for (int t = 0; t < C3; ++t)
            *(float4*)&bin[k & 1][t][tid * 4] = rr[t];
        __syncthreads();                             // bin[k&1] visible; bout(k-1) stores done
        if (k + 1 < NCH) {                           // prefetch under compute
            const float* nx = xbase + (size_t)(k + 1) * C3 * D_FEAT;
#pragma unroll
            for (int t = 0; t < C3; ++t)
                rr[t] = *(const float4*)&nx[(size_t)t * D_FEAT + tid * 4];
        }
        const float (*cb)[D_FEAT] = bin[k & 1];
#pragma unroll
        for (int r = 0; r < C3; ++r) {
            float vq[4];
#pragma unroll
            for (int jj = 0; jj < 4; ++jj) vq[jj] = cb[r][pcolq[jj]];
            float v[GD];
#pragma unroll
            for (int jj = 0; jj < 4; ++jj) {
                v[0  + jj] = qbc<0>(vq[jj]);
                v[4  + jj] = qbc<1>(vq[jj]);
                v[8  + jj] = qbc<2>(vq[jj]);
                v[12 + jj] = qbc<3>(vq[jj]);
            }
            float u[4] = {-bias[0], -bias[1], -bias[2], -bias[3]};
#pragma unroll
            for (int e = 0; e < GD; ++e)
#pragma unroll
                for (int ii = 0; ii < 4; ++ii) u[ii] = fmaf(v[e], w[e][ii], u[ii]);
#pragma unroll
            for (int ii = 0; ii < 4; ++ii) bout[r][pcolq[ii]] = u[ii];
        }
        __syncthreads();                             // bout complete
        float* ob = obase + (size_t)k * C3 * D_FEAT;
#pragma unroll
        for (int t = 0; t < C3; ++t)
            *(float4*)&ob[(size_t)t * D_FEAT + tid * 4] =
                *(const float4*)&bout[t][tid * 4];
    }
}

extern "C" void kernel_launch(void* const* d_in, const int* in_sizes, int n_in,
                              void* d_out, int out_size, void* d_ws, size_t ws_size,
                              hipStream_t stream) {
    const float* x     = (const float*)d_in[0];
    const int*   perms = (const int*)d_in[1];
    float* out = (float*)d_out;
    float* ws  = (float*)d_ws;

    // Partials (3*256*17408 floats = 53.5 MB) live in d_out: it is 100 MB and
    // k_apply fully overwrites every element afterwards. ws only needs 2.1 MB.
    float* part = out;

    dim3 g1(P1, NVIEW);                              // 768 blocks = 3/CU
    k_stats_part<<<g1, 256, 0, stream>>>(x, perms, part);

    dim3 gr1((ENT + 255) / 256, PSPLIT);             // (204, 8)
    k_reduce1<<<gr1, 256, 0, stream>>>(part, ws + RED_OFF);
    k_reduce2<<<(ENT + 255) / 256, 256, 0, stream>>>(ws + RED_OFF, ws);

    k_invsqrt<<<NVIEW * NGROUP, 256, 0, stream>>>(ws);

    dim3 g3(NB / RPB3, NVIEW);                       // 768 blocks = 3/CU
    k_apply<<<g3, 256, 0, stream>>>(x, perms, ws, out);
}